// Round 1
// 215.732 us; speedup vs baseline: 1.0392x; 1.0392x over previous
//
#include <hip/hip_runtime.h>
#include <hip/hip_bf16.h>
#include <stdint.h>

typedef unsigned short u16;
typedef __attribute__((ext_vector_type(8))) short short8;
typedef __attribute__((ext_vector_type(16))) float f32x16;

#define B_DIM 4096
#define D_DIM 1024
#define H_DIM 1024
#define K_DIM 2048   // D + H
#define N_DIM 4096   // 4H
#define LN_EPS 1e-5f

// ---------- helpers ----------
__device__ __forceinline__ u16 f2bf(float f) {
    union { float f; uint32_t u; } v; v.f = f;
    uint32_t u = v.u;
    uint32_t r = (u + 0x7FFFu + ((u >> 16) & 1u)) >> 16;  // RNE
    return (u16)r;
}
__device__ __forceinline__ float bf2f(u16 h) {
    union { uint32_t u; float f; } v; v.u = ((uint32_t)h) << 16;
    return v.f;
}
__device__ __forceinline__ void gld16(const u16* g, u16* l) {
    __builtin_amdgcn_global_load_lds(
        (const __attribute__((address_space(1))) void*)g,
        (__attribute__((address_space(3))) void*)l,
        16, 0, 0);
}
__device__ __forceinline__ float sigm(float x) { return 1.0f / (1.0f + __expf(-x)); }
__device__ __forceinline__ float tanh_fast(float x) { return 1.0f - 2.0f / (__expf(2.0f * x) + 1.0f); }

// ---------- kernel 1: fused prep (unchanged) ----------
__global__ __launch_bounds__(256) void prep(const float* __restrict__ x,
                                            const float* __restrict__ h,
                                            const float* __restrict__ Wx,
                                            const float* __restrict__ Wh,
                                            u16* __restrict__ A,
                                            u16* __restrict__ Bt) {
    __shared__ u16 tile[64 * 64];
    const int t = threadIdx.x;
    if (blockIdx.x < 4096) {
        int id = blockIdx.x * 256 + t;
        int row = id >> 8;
        int col = (id & 255) * 8;
        const float* src = (col < D_DIM) ? (x + (size_t)row * D_DIM + col)
                                         : (h + (size_t)row * H_DIM + (col - D_DIM));
        float4 v0 = ((const float4*)src)[0];
        float4 v1 = ((const float4*)src)[1];
        union { u16 us[8]; uint4 u; } p;
        p.us[0] = f2bf(v0.x); p.us[1] = f2bf(v0.y); p.us[2] = f2bf(v0.z); p.us[3] = f2bf(v0.w);
        p.us[4] = f2bf(v1.x); p.us[5] = f2bf(v1.y); p.us[6] = f2bf(v1.z); p.us[7] = f2bf(v1.w);
        *(uint4*)(A + (size_t)id * 8) = p.u;
    } else {
        const int v = blockIdx.x - 4096;       // 0..2047 = 64 x 32
        const int n0 = (v & 63) * 64;
        const int k0 = (v >> 6) * 64;
        const int kl  = t >> 4;                // 0..15
        const int nl4 = (t & 15) * 4;          // 0..60
#pragma unroll
        for (int it = 0; it < 4; ++it) {
            const int klocal = kl + it * 16;
            const int k = k0 + klocal;
            const float* src = (k < D_DIM) ? (Wx + (size_t)k * N_DIM)
                                           : (Wh + (size_t)(k - D_DIM) * N_DIM);
            float4 w = *(const float4*)(src + n0 + nl4);
            union { u16 us[4]; uint2 u; } p;
            p.us[0] = f2bf(w.x); p.us[1] = f2bf(w.y); p.us[2] = f2bf(w.z); p.us[3] = f2bf(w.w);
            const int swz = 8 * ((klocal >> 4) & 3);
            *(uint2*)(tile + klocal * 64 + (nl4 ^ swz)) = p.u;
        }
        __syncthreads();
        const int nl = t >> 2;
        const int kp = (t & 3) * 16;
        const int swz = 8 * (t & 3);
        union { u16 us[16]; uint4 q[2]; } o;
#pragma unroll
        for (int i = 0; i < 16; ++i)
            o.us[i] = tile[(kp + i) * 64 + (nl ^ swz)];
        u16* dst = Bt + (size_t)(n0 + nl) * K_DIM + k0 + kp;
        *(uint4*)dst = o.q[0];
        *(uint4*)(dst + 8) = o.q[1];
    }
}

// ---------- kernel 2: GEMM a = A @ Bt^T + bias -> bf16 [4096][4096] ----------
// 256x256 block, 8 waves (2Mx4N), 128x64 per wave (4x2 of 32x32x16), BK=64.
// Phase-split pipeline (T3+T4+T5): each K-tile = 2 phases (one per k-half).
// Phase = { 12x ds_read_b128 frags ; issue 1 k-half prefetch (4x gld16) ;
//           s_waitcnt vmcnt(8) ; s_barrier ; setprio(1) ; 16 MFMA ;
//           setprio(0) ; s_barrier }.
// vmcnt(8) = 2 stage-calls (each 4 loads) stay in flight across barriers;
// issue-to-use distance = 3 phases. A prefetch always targets the k-half
// whose reads completed before the PREVIOUS end-of-phase barrier:
//   P(t,0) stages (buf^1, t+1, kh1)  [buf^1.kh1 last read at P(t-1,1)]
//   P(t,1) stages (buf,   t+2, kh0)  [buf.kh0   last read at P(t,0)]
// LDS geometry per k-half: [256 rows][32 u16]; 4 16B-blocks per row, stored
// block s holds global block g = (s - (row>>1)) & 3; fragment read
// s = (g + (lr>>1)) & 3 (same measured class as the verified kernel).
__global__ __launch_bounds__(512, 2) void gemm_bf16(const u16* __restrict__ A,   // [4096][2048]
                                                    const u16* __restrict__ Bt,  // [4096][2048]
                                                    const float* __restrict__ bias,
                                                    u16* __restrict__ C) {       // [4096][4096]
    __shared__ u16 As[2][16384];   // [buf][kh*8192 + row*32 + s*8]
    __shared__ u16 Bs[2][16384];
    const int tid = threadIdx.x;
    const int wave = tid >> 6, lane = tid & 63;

    // bijective XCD swizzle: 256 wgs, 8 XCDs -> each XCD gets 2 contiguous
    // M-panels (2 MB of A resident per XCD L2)
    const int bid = blockIdx.y * 16 + blockIdx.x;
    const int swz_bid = (bid & 7) * 32 + (bid >> 3);
    const int m0 = (swz_bid >> 4) * 256;
    const int n0 = (swz_bid & 15) * 256;

    const int wm = (wave & 1) * 128;     // 2 waves along M
    const int wn = (wave >> 1) * 64;     // 4 waves along N

    f32x16 acc[4][2] = {};

    // staging: chunk = 16 rows x 32 u16 = 1KB; per k-half 16 chunks; each
    // wave stages 2 chunks per matrix per k-half (= 4 gld16 per call).
    const int perm = ((lane & 3) - (lane >> 3)) & 3;
    const int vofs = (lane >> 2) * K_DIM + perm * 8;
    const int lr = lane & 31, half = lane >> 5;

    const u16* Ab = A  + (size_t)m0 * K_DIM;
    const u16* Bb = Bt + (size_t)n0 * K_DIM;

    auto stage = [&](int buf, int t, int h) {
        const int kt = t * 64;
#pragma unroll
        for (int q = 0; q < 2; ++q) {
            const int c = wave * 2 + q;                       // 0..15
            const int so = (c * 16) * K_DIM + kt + h * 32;    // wave-uniform
            const int ldso = h * 8192 + c * 512;
            gld16(Ab + so + vofs, &As[buf][ldso]);
            gld16(Bb + so + vofs, &Bs[buf][ldso]);
        }
    };

#define VMWAIT(n) asm volatile("s_waitcnt vmcnt(" #n ")" ::: "memory")

#define PHASE(BUF, KH, STAGE_STMT, VM)                                               \
    {                                                                                \
        short8 af[2][4], bfr[2][2];                                                  \
        _Pragma("unroll")                                                            \
        for (int kk2 = 0; kk2 < 2; ++kk2) {                                          \
            const int s = ((kk2 * 2 + half) + (lr >> 1)) & 3;                        \
            const int ko = (KH) * 8192 + s * 8;                                      \
            _Pragma("unroll")                                                        \
            for (int i = 0; i < 4; ++i)                                              \
                af[kk2][i] = *(const short8*)(&As[BUF][ko + (wm + i * 32 + lr) * 32]); \
            _Pragma("unroll")                                                        \
            for (int j = 0; j < 2; ++j)                                              \
                bfr[kk2][j] = *(const short8*)(&Bs[BUF][ko + (wn + j * 32 + lr) * 32]); \
        }                                                                            \
        STAGE_STMT;                                                                  \
        asm volatile("s_waitcnt vmcnt(" #VM ")" ::: "memory");                       \
        __builtin_amdgcn_s_barrier();                                                \
        __builtin_amdgcn_s_setprio(1);                                               \
        _Pragma("unroll")                                                            \
        for (int kk2 = 0; kk2 < 2; ++kk2)                                            \
            _Pragma("unroll")                                                        \
            for (int i = 0; i < 4; ++i)                                              \
                _Pragma("unroll")                                                    \
                for (int j = 0; j < 2; ++j)                                          \
                    acc[i][j] = __builtin_amdgcn_mfma_f32_32x32x16_bf16(             \
                        af[kk2][i], bfr[kk2][j], acc[i][j], 0, 0, 0);                \
        __builtin_amdgcn_s_setprio(0);                                               \
        __builtin_amdgcn_s_barrier();                                                \
    }

    // prologue: tile0 both halves + tile1 kh0; wait all but newest call
    stage(0, 0, 0);
    stage(0, 0, 1);
    stage(1, 1, 0);
    VMWAIT(4);
    __builtin_amdgcn_s_barrier();

    // main: 15 iterations x 2 K-tiles (t = 0..29), compile-time buf/kh
    for (int t2 = 0; t2 < 15; ++t2) {
        const int t = t2 * 2;
        PHASE(0, 0, stage(1, t + 1, 1), 8);
        PHASE(0, 1, stage(0, t + 2, 0), 8);
        PHASE(1, 0, stage(0, t + 2, 1), 8);
        PHASE(1, 1, stage(1, t + 3, 0), 8);
    }
    // tail: t = 30 (buf0), t = 31 (buf1) with tightened waits
    PHASE(0, 0, stage(1, 31, 1), 8);
    PHASE(0, 1, ;, 4);   // ensures (t31,kh0) landed
    PHASE(1, 0, ;, 0);   // ensures (t31,kh1) landed
    PHASE(1, 1, ;, 0);

#undef PHASE
#undef VMWAIT

    // epilogue: 32x32 C/D layout col=lane&31, row=(reg&3)+8*(reg>>2)+4*(lane>>5)
#pragma unroll
    for (int i = 0; i < 4; ++i) {
#pragma unroll
        for (int j = 0; j < 2; ++j) {
            const int c = n0 + wn + 32 * j + lr;
            const float bb = bias[c];
#pragma unroll
            for (int reg = 0; reg < 16; ++reg) {
                const int row = m0 + wm + 32 * i + (reg & 3) + 8 * (reg >> 2) + 4 * half;
                C[(size_t)row * N_DIM + c] = f2bf(acc[i][j][reg] + bb);
            }
        }
    }
}

// ---------- kernel 3: LayerNorm + gates + cell update (unchanged) ----------
__global__ __launch_bounds__(256) void ln_lstm(const u16* __restrict__ aT,     // [4096][4096] bf16
                                               const float* __restrict__ pc,   // prev_c
                                               const float* __restrict__ gamma,
                                               const float* __restrict__ beta,
                                               float* __restrict__ out) {      // [h | c]
    const int row = blockIdx.x;
    const int t = threadIdx.x;
    const u16* ar = aT + (size_t)row * N_DIM;
    const int j0 = t * 4;

    union U2 { uint2 u; u16 us[4]; };
    U2 g4[4];
#pragma unroll
    for (int s = 0; s < 4; ++s) g4[s].u = *(const uint2*)(ar + s * H_DIM + j0);

    float sum = 0.f, ssq = 0.f;
#pragma unroll
    for (int s = 0; s < 4; ++s)
#pragma unroll
        for (int e = 0; e < 4; ++e) { float v = bf2f(g4[s].us[e]); sum += v; ssq += v * v; }

#pragma unroll
    for (int off = 32; off > 0; off >>= 1) {
        sum += __shfl_down(sum, off, 64);
        ssq += __shfl_down(ssq, off, 64);
    }
    __shared__ float red[8];
    if ((t & 63) == 0) { red[t >> 6] = sum; red[4 + (t >> 6)] = ssq; }
    __syncthreads();
    const float ts = red[0] + red[1] + red[2] + red[3];
    const float tq = red[4] + red[5] + red[6] + red[7];
    const float mu = ts * (1.0f / N_DIM);
    const float var = fmaxf(tq * (1.0f / N_DIM) - mu * mu, 0.0f);
    const float rs = rsqrtf(var + LN_EPS);

    float vi[4], vf[4], vo[4], vg[4];
    auto gate = [&](int s, float* v) {
        const int off = s * H_DIM;
        float4 gm = *(const float4*)(gamma + off + j0);
        float4 bt = *(const float4*)(beta + off + j0);
        v[0] = (bf2f(g4[s].us[0]) - mu) * rs * gm.x + bt.x;
        v[1] = (bf2f(g4[s].us[1]) - mu) * rs * gm.y + bt.y;
        v[2] = (bf2f(g4[s].us[2]) - mu) * rs * gm.z + bt.z;
        v[3] = (bf2f(g4[s].us[3]) - mu) * rs * gm.w + bt.w;
    };
    gate(0, vi); gate(1, vf); gate(2, vo); gate(3, vg);

    float4 c4 = *(const float4*)(pc + (size_t)row * H_DIM + j0);
    float cin[4] = {c4.x, c4.y, c4.z, c4.w};
    float nh[4], nc[4];
#pragma unroll
    for (int r = 0; r < 4; ++r) {
        float ig = sigm(vi[r]);
        float fg = sigm(vf[r]);
        float og = sigm(vo[r]);
        float gg = tanh_fast(vg[r]);
        nc[r] = fg * cin[r] + ig * gg;
        nh[r] = og * tanh_fast(nc[r]);
    }
    float4 h4 = {nh[0], nh[1], nh[2], nh[3]};
    float4 c4o = {nc[0], nc[1], nc[2], nc[3]};
    *(float4*)(out + (size_t)row * H_DIM + j0) = h4;
    *(float4*)(out + (size_t)B_DIM * H_DIM + (size_t)row * H_DIM + j0) = c4o;
}

// ---------- launch ----------
extern "C" void kernel_launch(void* const* d_in, const int* in_sizes, int n_in,
                              void* d_out, int out_size, void* d_ws, size_t ws_size,
                              hipStream_t stream) {
    const float* x  = (const float*)d_in[0];
    const float* ph = (const float*)d_in[1];
    const float* pc = (const float*)d_in[2];
    const float* Wx = (const float*)d_in[3];
    const float* Wh = (const float*)d_in[4];
    const float* b  = (const float*)d_in[5];
    const float* gm = (const float*)d_in[6];
    const float* bt = (const float*)d_in[7];
    float* out = (float*)d_out;

    char* ws = (char*)d_ws;
    u16* Abf = (u16*)ws;                               // 16 MiB: [4096][2048] bf16
    u16* Btb = (u16*)(ws + (size_t)16 * 1024 * 1024);  // 16 MiB: [4096][2048] bf16
    u16* aT  = (u16*)(ws + (size_t)32 * 1024 * 1024);  // 32 MiB: [4096][4096] bf16

    prep<<<dim3(4096 + 2048), dim3(256), 0, stream>>>(x, ph, Wx, Wh, Abf, Btb);
    gemm_bf16<<<dim3(16, 16), dim3(512), 0, stream>>>(Abf, Btb, b, aT);
    ln_lstm<<<dim3(4096), dim3(256), 0, stream>>>(aT, pc, gm, bt, out);
}

// Round 2
// 214.799 us; speedup vs baseline: 1.0437x; 1.0043x over previous
//
#include <hip/hip_runtime.h>
#include <hip/hip_bf16.h>
#include <stdint.h>

typedef unsigned short u16;
typedef __attribute__((ext_vector_type(8))) short short8;
typedef __attribute__((ext_vector_type(16))) float f32x16;

#define B_DIM 4096
#define D_DIM 1024
#define H_DIM 1024
#define K_DIM 2048   // D + H
#define N_DIM 4096   // 4H
#define LN_EPS 1e-5f

// ---------- helpers ----------
__device__ __forceinline__ u16 f2bf(float f) {
    union { float f; uint32_t u; } v; v.f = f;
    uint32_t u = v.u;
    uint32_t r = (u + 0x7FFFu + ((u >> 16) & 1u)) >> 16;  // RNE
    return (u16)r;
}
__device__ __forceinline__ float bf2f(u16 h) {
    union { uint32_t u; float f; } v; v.u = ((uint32_t)h) << 16;
    return v.f;
}
__device__ __forceinline__ void gld16(const u16* g, u16* l) {
    __builtin_amdgcn_global_load_lds(
        (const __attribute__((address_space(1))) void*)g,
        (__attribute__((address_space(3))) void*)l,
        16, 0, 0);
}
__device__ __forceinline__ float sigm(float x) { return 1.0f / (1.0f + __expf(-x)); }
__device__ __forceinline__ float tanh_fast(float x) { return 1.0f - 2.0f / (__expf(2.0f * x) + 1.0f); }

// ---------- kernel 1: fused prep (unchanged) ----------
__global__ __launch_bounds__(256) void prep(const float* __restrict__ x,
                                            const float* __restrict__ h,
                                            const float* __restrict__ Wx,
                                            const float* __restrict__ Wh,
                                            u16* __restrict__ A,
                                            u16* __restrict__ Bt) {
    __shared__ u16 tile[64 * 64];
    const int t = threadIdx.x;
    if (blockIdx.x < 4096) {
        int id = blockIdx.x * 256 + t;
        int row = id >> 8;
        int col = (id & 255) * 8;
        const float* src = (col < D_DIM) ? (x + (size_t)row * D_DIM + col)
                                         : (h + (size_t)row * H_DIM + (col - D_DIM));
        float4 v0 = ((const float4*)src)[0];
        float4 v1 = ((const float4*)src)[1];
        union { u16 us[8]; uint4 u; } p;
        p.us[0] = f2bf(v0.x); p.us[1] = f2bf(v0.y); p.us[2] = f2bf(v0.z); p.us[3] = f2bf(v0.w);
        p.us[4] = f2bf(v1.x); p.us[5] = f2bf(v1.y); p.us[6] = f2bf(v1.z); p.us[7] = f2bf(v1.w);
        *(uint4*)(A + (size_t)id * 8) = p.u;
    } else {
        const int v = blockIdx.x - 4096;       // 0..2047 = 64 x 32
        const int n0 = (v & 63) * 64;
        const int k0 = (v >> 6) * 64;
        const int kl  = t >> 4;                // 0..15
        const int nl4 = (t & 15) * 4;          // 0..60
#pragma unroll
        for (int it = 0; it < 4; ++it) {
            const int klocal = kl + it * 16;
            const int k = k0 + klocal;
            const float* src = (k < D_DIM) ? (Wx + (size_t)k * N_DIM)
                                           : (Wh + (size_t)(k - D_DIM) * N_DIM);
            float4 w = *(const float4*)(src + n0 + nl4);
            union { u16 us[4]; uint2 u; } p;
            p.us[0] = f2bf(w.x); p.us[1] = f2bf(w.y); p.us[2] = f2bf(w.z); p.us[3] = f2bf(w.w);
            const int swz = 8 * ((klocal >> 4) & 3);
            *(uint2*)(tile + klocal * 64 + (nl4 ^ swz)) = p.u;
        }
        __syncthreads();
        const int nl = t >> 2;
        const int kp = (t & 3) * 16;
        const int swz = 8 * (t & 3);
        union { u16 us[16]; uint4 q[2]; } o;
#pragma unroll
        for (int i = 0; i < 16; ++i)
            o.us[i] = tile[(kp + i) * 64 + (nl ^ swz)];
        u16* dst = Bt + (size_t)(n0 + nl) * K_DIM + k0 + kp;
        *(uint4*)dst = o.q[0];
        *(uint4*)(dst + 8) = o.q[1];
    }
}

// ---------- kernel 2: GEMM a = A @ Bt^T + bias -> bf16 [4096][4096] ----------
// 256x256 block, 8 waves (2M x 4N), per-wave 128x64 (acc[4][2] of 32x32x16).
// BK=64 split as 2 K-halves (ks). LDS per matrix: [buf][ks][256 rows][32 u16],
// XOR-swizzled at 16B-block granularity: stored block q holds global block
// q ^ ((row>>1)&3). Every 16-lane quarter of a ds_read_b128 then covers all
// 32 banks exactly 2x (conflict-free class). Staged with LINEAR gld16 dest +
// inverse-swizzled per-lane SOURCE (both-sides rule).
//
// Schedule (8 phases / 2 K-tiles, ONE barrier per phase, MFMA consumes
// ds_reads directly -> compiler fine-grained lgkmcnt overlap):
//  ph1 (b0,ks0,qj0) reads A(ks0)+B    stage A(t+1,ks1)->b1
//  ph2 (b0,ks0,qj1) reads B           stage B(t+1,ks1)->b1   vmcnt(8)
//  ph3 (b0,ks1,qj1) reads A(ks1)+B    stage A(t+2,ks0)->b0
//  ph4 (b0,ks1,qj0) reads B           stage B(t+2,ks0)->b0   vmcnt(8)
//  ph5 (b1,ks0,qj0) reads A(ks0)+B    stage A(t+2,ks1)->b0
//  ph6 (b1,ks0,qj1) reads B           stage B(t+2,ks1)->b0   vmcnt(8)
//  ph7 (b1,ks1,qj1) reads A(ks1)+B    stage A(t+3,ks0)->b1
//  ph8 (b1,ks1,qj0) reads B           stage B(t+3,ks0)->b1   vmcnt(8)
// Each stage-unit (2 gld16) is issued exactly one phase after its half's
// last LDS read (WAR-safe), and vmcnt(8) at even phases guarantees a unit
// 4-6 phases after issue, one phase before its first read. vmcnt never 0 in
// the loop. Tail iterations stage out-of-range tiles (reads land in mapped
// workspace, data never consumed) so steady-state vmcnt accounting holds.
__global__ __launch_bounds__(512, 2) void gemm_bf16(const u16* __restrict__ A,   // [4096][2048]
                                                    const u16* __restrict__ Bt,  // [4096][2048]
                                                    const float* __restrict__ bias,
                                                    u16* __restrict__ C) {       // [4096][4096]
    __shared__ u16 As[2][2][8192];   // [buf][ks][row*32 + swizzled col]
    __shared__ u16 Bs[2][2][8192];
    const int tid = threadIdx.x;
    const int wave = tid >> 6, lane = tid & 63;

    // bijective XCD swizzle (256 wgs % 8 == 0)
    const int bid = blockIdx.y * 16 + blockIdx.x;
    const int swz_bid = (bid & 7) * 32 + (bid >> 3);
    const int m0 = (swz_bid >> 4) * 256;
    const int n0 = (swz_bid & 15) * 256;

    const int wr = wave & 1, wc = wave >> 1;
    const int wm = wr * 128, wn = wc * 64;
    const int lr = lane & 31, half = lane >> 5;

    f32x16 acc[4][2] = {};

    // ---- staging constants ----
    // dest (linear): row = pass*128 + wave*16 + (lane>>2), 16B-block = lane&3
    // src 16B-block = (lane&3) ^ s(row), s(row) = (row>>1)&3 = (lane>>3)&3
    const int srow = wave * 16 + (lane >> 2);
    const int qsrc = (lane & 3) ^ ((lane >> 3) & 3);
    const u16* Asrc = A  + (size_t)(m0 + srow) * K_DIM + qsrc * 8;
    const u16* Bsrc = Bt + (size_t)(n0 + srow) * K_DIM + qsrc * 8;
    const int ldst = wave * 512;   // u16; + pass*4096

    auto stageA = [&](int buf, int tt, int ks) {
        const int ko = tt * 64 + ks * 32;
        gld16(Asrc + ko,                         &As[buf][ks][ldst]);
        gld16(Asrc + ko + (size_t)128 * K_DIM,   &As[buf][ks][ldst + 4096]);
    };
    auto stageB = [&](int buf, int tt, int ks) {
        const int ko = tt * 64 + ks * 32;
        gld16(Bsrc + ko,                         &Bs[buf][ks][ldst]);
        gld16(Bsrc + ko + (size_t)128 * K_DIM,   &Bs[buf][ks][ldst + 4096]);
    };

    // ---- fragment read constants ----
    // A-frag(i,kk): row = wm + i*32 + lr, block q = kk*2 + half, read at
    // row*32 + ((q ^ sA)<<3), sA = (lr>>1)&3 (lane-const since row bits 1-2 = lr bits 1-2)
    const int sA = (lr >> 1) & 3;
    const int aoff = (wm + lr) * 32;
    const int boff = (wn + lr) * 32;

    short8 af[2][4], bf[2];

#define PHASE(BUF, KS, QJ, READ_A, STAGE_STMT, DO_VM)                                  \
    {                                                                                  \
        if (READ_A) {                                                                  \
            _Pragma("unroll")                                                          \
            for (int kk = 0; kk < 2; ++kk)                                             \
                _Pragma("unroll")                                                      \
                for (int i = 0; i < 4; ++i)                                            \
                    af[kk][i] = *(const short8*)(                                      \
                        &As[BUF][KS][aoff + i * 1024 + (((kk * 2 + half) ^ sA) << 3)]);\
        }                                                                              \
        _Pragma("unroll")                                                              \
        for (int kk = 0; kk < 2; ++kk)                                                 \
            bf[kk] = *(const short8*)(                                                 \
                &Bs[BUF][KS][boff + (QJ) * 1024 + (((kk * 2 + half) ^ sA) << 3)]);     \
        STAGE_STMT;                                                                    \
        __builtin_amdgcn_s_setprio(1);                                                 \
        _Pragma("unroll")                                                              \
        for (int kk = 0; kk < 2; ++kk)                                                 \
            _Pragma("unroll")                                                          \
            for (int i = 0; i < 4; ++i)                                                \
                acc[i][QJ] = __builtin_amdgcn_mfma_f32_32x32x16_bf16(                  \
                    af[kk][i], bf[kk], acc[i][QJ], 0, 0, 0);                           \
        __builtin_amdgcn_s_setprio(0);                                                 \
        if (DO_VM) asm volatile("s_waitcnt vmcnt(8)" ::: "memory");                    \
        __builtin_amdgcn_s_barrier();                                                  \
        asm volatile("" ::: "memory");                                                 \
    }

    // prologue: tile0 (both halves) + tile1 ks0; drain; barrier
    stageA(0, 0, 0); stageB(0, 0, 0);
    stageA(0, 0, 1); stageB(0, 0, 1);
    stageA(1, 1, 0); stageB(1, 1, 0);
    asm volatile("s_waitcnt vmcnt(0)" ::: "memory");
    __builtin_amdgcn_s_barrier();
    asm volatile("" ::: "memory");

    for (int it = 0; it < 16; ++it) {
        const int t = it * 2;
        // tile t (buf0)
        PHASE(0, 0, 0, true,  stageA(1, t + 1, 1), false);
        PHASE(0, 0, 1, false, stageB(1, t + 1, 1), true );
        PHASE(0, 1, 1, true,  stageA(0, t + 2, 0), false);
        PHASE(0, 1, 0, false, stageB(0, t + 2, 0), true );
        // tile t+1 (buf1)
        PHASE(1, 0, 0, true,  stageA(0, t + 2, 1), false);
        PHASE(1, 0, 1, false, stageB(0, t + 2, 1), true );
        PHASE(1, 1, 1, true,  stageA(1, t + 3, 0), false);
        PHASE(1, 1, 0, false, stageB(1, t + 3, 0), true );
    }
#undef PHASE

    // epilogue: 32x32 C/D layout col=lane&31, row=(reg&3)+8*(reg>>2)+4*(lane>>5)
#pragma unroll
    for (int i = 0; i < 4; ++i) {
#pragma unroll
        for (int j = 0; j < 2; ++j) {
            const int c = n0 + wn + 32 * j + lr;
            const float bb = bias[c];
#pragma unroll
            for (int reg = 0; reg < 16; ++reg) {
                const int row = m0 + wm + 32 * i + (reg & 3) + 8 * (reg >> 2) + 4 * half;
                C[(size_t)row * N_DIM + c] = f2bf(acc[i][j][reg] + bb);
            }
        }
    }
}

// ---------- kernel 3: LayerNorm + gates + cell update (unchanged) ----------
__global__ __launch_bounds__(256) void ln_lstm(const u16* __restrict__ aT,     // [4096][4096] bf16
                                               const float* __restrict__ pc,   // prev_c
                                               const float* __restrict__ gamma,
                                               const float* __restrict__ beta,
                                               float* __restrict__ out) {      // [h | c]
    const int row = blockIdx.x;
    const int t = threadIdx.x;
    const u16* ar = aT + (size_t)row * N_DIM;
    const int j0 = t * 4;

    union U2 { uint2 u; u16 us[4]; };
    U2 g4[4];
#pragma unroll
    for (int s = 0; s < 4; ++s) g4[s].u = *(const uint2*)(ar + s * H_DIM + j0);

    float sum = 0.f, ssq = 0.f;
#pragma unroll
    for (int s = 0; s < 4; ++s)
#pragma unroll
        for (int e = 0; e < 4; ++e) { float v = bf2f(g4[s].us[e]); sum += v; ssq += v * v; }

#pragma unroll
    for (int off = 32; off > 0; off >>= 1) {
        sum += __shfl_down(sum, off, 64);
        ssq += __shfl_down(ssq, off, 64);
    }
    __shared__ float red[8];
    if ((t & 63) == 0) { red[t >> 6] = sum; red[4 + (t >> 6)] = ssq; }
    __syncthreads();
    const float ts = red[0] + red[1] + red[2] + red[3];
    const float tq = red[4] + red[5] + red[6] + red[7];
    const float mu = ts * (1.0f / N_DIM);
    const float var = fmaxf(tq * (1.0f / N_DIM) - mu * mu, 0.0f);
    const float rs = rsqrtf(var + LN_EPS);

    float vi[4], vf[4], vo[4], vg[4];
    auto gate = [&](int s, float* v) {
        const int off = s * H_DIM;
        float4 gm = *(const float4*)(gamma + off + j0);
        float4 bt = *(const float4*)(beta + off + j0);
        v[0] = (bf2f(g4[s].us[0]) - mu) * rs * gm.x + bt.x;
        v[1] = (bf2f(g4[s].us[1]) - mu) * rs * gm.y + bt.y;
        v[2] = (bf2f(g4[s].us[2]) - mu) * rs * gm.z + bt.z;
        v[3] = (bf2f(g4[s].us[3]) - mu) * rs * gm.w + bt.w;
    };
    gate(0, vi); gate(1, vf); gate(2, vo); gate(3, vg);

    float4 c4 = *(const float4*)(pc + (size_t)row * H_DIM + j0);
    float cin[4] = {c4.x, c4.y, c4.z, c4.w};
    float nh[4], nc[4];
#pragma unroll
    for (int r = 0; r < 4; ++r) {
        float ig = sigm(vi[r]);
        float fg = sigm(vf[r]);
        float og = sigm(vo[r]);
        float gg = tanh_fast(vg[r]);
        nc[r] = fg * cin[r] + ig * gg;
        nh[r] = og * tanh_fast(nc[r]);
    }
    float4 h4 = {nh[0], nh[1], nh[2], nh[3]};
    float4 c4o = {nc[0], nc[1], nc[2], nc[3]};
    *(float4*)(out + (size_t)row * H_DIM + j0) = h4;
    *(float4*)(out + (size_t)B_DIM * H_DIM + (size_t)row * H_DIM + j0) = c4o;
}

// ---------- launch ----------
extern "C" void kernel_launch(void* const* d_in, const int* in_sizes, int n_in,
                              void* d_out, int out_size, void* d_ws, size_t ws_size,
                              hipStream_t stream) {
    const float* x  = (const float*)d_in[0];
    const float* ph = (const float*)d_in[1];
    const float* pc = (const float*)d_in[2];
    const float* Wx = (const float*)d_in[3];
    const float* Wh = (const float*)d_in[4];
    const float* b  = (const float*)d_in[5];
    const float* gm = (const float*)d_in[6];
    const float* bt = (const float*)d_in[7];
    float* out = (float*)d_out;

    char* ws = (char*)d_ws;
    u16* Abf = (u16*)ws;                               // 16 MiB: [4096][2048] bf16
    u16* Btb = (u16*)(ws + (size_t)16 * 1024 * 1024);  // 16 MiB: [4096][2048] bf16
    u16* aT  = (u16*)(ws + (size_t)32 * 1024 * 1024);  // 32 MiB: [4096][4096] bf16

    prep<<<dim3(4096 + 2048), dim3(256), 0, stream>>>(x, ph, Wx, Wh, Abf, Btb);
    gemm_bf16<<<dim3(16, 16), dim3(512), 0, stream>>>(Abf, Btb, b, aT);
    ln_lstm<<<dim3(4096), dim3(256), 0, stream>>>(aT, pc, gm, bt, out);
}